// Round 3
// baseline (2261.999 us; speedup 1.0000x reference)
//
#include <hip/hip_runtime.h>

// ---------------------------------------------------------------------------
// GCN: out = spmm(A, relu(spmm(A, x)@w1 + b1)) @ w2 + b2
// Reordered: y1 = x@w1 ; h1 = relu(spmm(y1)+b1) ; y2 = h1@w2 ; out = spmm(y2)+b2
// R3: coarse 128-row bucketing (no full sort) + LDS-accumulator spmm.
//     Partition writes bucket-ordered packed edges {col|rl<<17, val} coalesced
//     via LDS staging. spmm: 1 block/bucket, acc[128][CH] in LDS, ds_add_f32.
// ---------------------------------------------------------------------------

typedef __bf16 v8bf __attribute__((ext_vector_type(8)));
typedef float  v4f  __attribute__((ext_vector_type(4)));

#define MAXB 800  // max buckets (N<=102400)

__device__ __forceinline__ unsigned short f2bf(float f) {
    unsigned u = __float_as_uint(f);
    unsigned r = u + 0x7fffu + ((u >> 16) & 1u);   // RNE
    return (unsigned short)(r >> 16);
}

// ---- bucket histogram (LDS-aggregated) ------------------------------------
__global__ __launch_bounds__(256) void hist_b(const int* __restrict__ arow,
                                              int* __restrict__ counts, int E, int B) {
    __shared__ int lh[MAXB];
    const int tid = threadIdx.x;
    for (int i = tid; i < B; i += 256) lh[i] = 0;
    __syncthreads();
    const int base = blockIdx.x * 4096;
#pragma unroll
    for (int j = 0; j < 16; ++j) {
        int i = base + j * 256 + tid;
        if (i < E) atomicAdd(&lh[arow[i] >> 7], 1);
    }
    __syncthreads();
    for (int i = tid; i < B; i += 256) {
        int c = lh[i];
        if (c) atomicAdd(&counts[i], c);
    }
}

// ---- single-block exclusive scan over B<=1024 bucket counts ---------------
__global__ __launch_bounds__(256) void scan_s(const int* __restrict__ counts,
                                              int* __restrict__ boff,
                                              int* __restrict__ gcursor, int B, int E) {
    __shared__ int lds[256];
    const int t = threadIdx.x;
    const int b0 = t * 4;
    int v[4];
    int s = 0;
#pragma unroll
    for (int j = 0; j < 4; ++j) {
        v[j] = (b0 + j < B) ? counts[b0 + j] : 0;
        s += v[j];
    }
    lds[t] = s;
    __syncthreads();
    for (int off = 1; off < 256; off <<= 1) {
        int tmp = 0;
        if (t >= off) tmp = lds[t - off];
        __syncthreads();
        if (t >= off) lds[t] += tmp;
        __syncthreads();
    }
    int run = (t > 0) ? lds[t - 1] : 0;
#pragma unroll
    for (int j = 0; j < 4; ++j) {
        if (b0 + j < B) {
            boff[b0 + j] = run;
            gcursor[b0 + j] = run;
        }
        run += v[j];
    }
    if (t == 255) boff[B] = E;
}

// ---- partition: bucket-order edges with LDS staging (coalesced out) -------
__global__ __launch_bounds__(256) void partition_k(const int* __restrict__ arow,
                                                   const int* __restrict__ acol,
                                                   const float* __restrict__ aval,
                                                   int* __restrict__ gcursor,
                                                   int2* __restrict__ epk, int E, int B) {
    __shared__ int2 ldata[4096];
    __shared__ int ldest[4096];
    __shared__ int lhist[MAXB];
    __shared__ int lscan[MAXB];
    __shared__ int ldelta[MAXB];
    __shared__ int lcur[MAXB];
    __shared__ int stmp[256];
    const int tid = threadIdx.x;
    const int base = blockIdx.x * 4096;
    const int cnt = min(4096, E - base);

    for (int i = tid; i < MAXB; i += 256) {
        lhist[i] = 0;
        lcur[i] = 0;
    }
    __syncthreads();

    int rr[16];
#pragma unroll
    for (int j = 0; j < 16; ++j) {
        int i = base + j * 256 + tid;
        rr[j] = (i < E) ? arow[i] : -1;
        if (rr[j] >= 0) atomicAdd(&lhist[rr[j] >> 7], 1);
    }
    __syncthreads();

    // exclusive scan of lhist -> lscan (256 thr x 4)
    const int b0 = tid * 4;
    int v[4];
    int s = 0;
#pragma unroll
    for (int j = 0; j < 4; ++j) {
        v[j] = (b0 + j < MAXB) ? lhist[b0 + j] : 0;
        s += v[j];
    }
    stmp[tid] = s;
    __syncthreads();
    for (int off = 1; off < 256; off <<= 1) {
        int tmp = 0;
        if (tid >= off) tmp = stmp[tid - off];
        __syncthreads();
        if (tid >= off) stmp[tid] += tmp;
        __syncthreads();
    }
    int run = (tid > 0) ? stmp[tid - 1] : 0;
#pragma unroll
    for (int j = 0; j < 4; ++j) {
        if (b0 + j < MAXB) lscan[b0 + j] = run;
        run += v[j];
    }
    __syncthreads();

    // reserve global ranges
    for (int b = tid; b < B; b += 256) {
        int c = lhist[b];
        if (c) ldelta[b] = atomicAdd(&gcursor[b], c) - lscan[b];
    }
    __syncthreads();

    // scatter into LDS staging
#pragma unroll
    for (int j = 0; j < 16; ++j) {
        int i = base + j * 256 + tid;
        if (i < E) {
            int r = rr[j];
            int b = r >> 7;
            int lp = atomicAdd(&lcur[b], 1);
            int slot = lscan[b] + lp;
            int pk = acol[i] | ((r & 127) << 17);
            ldata[slot] = make_int2(pk, __float_as_int(aval[i]));
            ldest[slot] = ldelta[b] + slot;
        }
    }
    __syncthreads();

    // coalesced copy-out (dest monotone within bucket runs)
    for (int s2 = tid; s2 < cnt; s2 += 256) epk[ldest[s2]] = ldata[s2];
}

// ---- cast + transpose weights: w[K][NC] fp32 -> wT[NC][K] bf16 ------------
__global__ void cast_transpose_w(const float* __restrict__ w, unsigned short* __restrict__ wT,
                                 int K, int NC) {
    int i = blockIdx.x * blockDim.x + threadIdx.x;
    if (i < K * NC) {
        int k = i / NC, n = i - k * NC;
        wT[n * K + k] = f2bf(w[i]);
    }
}

// ---- MFMA GEMM: y_bf16[M x NC] = A[M x 128] @ W[128 x NC] -----------------
template <int NC, bool AF32>
__global__ __launch_bounds__(256) void gemm_mfma(const void* __restrict__ A,
                                                 const unsigned short* __restrict__ wT,
                                                 unsigned short* __restrict__ y, int M) {
    constexpr int KP = 136;
    constexpr int NT = NC / 16;
    __shared__ unsigned short wl[NC * KP];
    const int tid = threadIdx.x;
    for (int idx = tid; idx < NC * 16; idx += 256) {
        int n = idx >> 4, kc = idx & 15;
        *(uint4*)&wl[n * KP + kc * 8] = *(const uint4*)&wT[n * 128 + kc * 8];
    }
    __syncthreads();

    const int wave = tid >> 6;
    const int lane = tid & 63;
    const int m = lane & 15;
    const int q = lane >> 4;
    const int rowbase = blockIdx.x * 64 + wave * 16;
    const int rowc = min(rowbase + m, M - 1);

    v4f acc[NT] = {};
    union LU { uint4 qv; v8bf b; };

#pragma unroll
    for (int ks = 0; ks < 4; ++ks) {
        const int k0 = ks * 32 + q * 8;
        v8bf a;
        if (AF32) {
            const float* Ap = (const float*)A + (size_t)rowc * 128 + k0;
            float4 f0 = *(const float4*)Ap;
            float4 f1 = *(const float4*)(Ap + 4);
            union { unsigned short s[8]; v8bf b; } cv;
            cv.s[0] = f2bf(f0.x); cv.s[1] = f2bf(f0.y);
            cv.s[2] = f2bf(f0.z); cv.s[3] = f2bf(f0.w);
            cv.s[4] = f2bf(f1.x); cv.s[5] = f2bf(f1.y);
            cv.s[6] = f2bf(f1.z); cv.s[7] = f2bf(f1.w);
            a = cv.b;
        } else {
            LU lu;
            lu.qv = *(const uint4*)((const unsigned short*)A + (size_t)rowc * 128 + k0);
            a = lu.b;
        }
#pragma unroll
        for (int nt = 0; nt < NT; ++nt) {
            v8bf b = *(const v8bf*)&wl[(nt * 16 + m) * KP + k0];
            acc[nt] = __builtin_amdgcn_mfma_f32_16x16x32_bf16(a, b, acc[nt], 0, 0, 0);
        }
    }
#pragma unroll
    for (int nt = 0; nt < NT; ++nt) {
#pragma unroll
        for (int r = 0; r < 4; ++r) {
            int orow = rowbase + q * 4 + r;
            if (orow < M) y[(size_t)orow * NC + nt * 16 + m] = f2bf(acc[nt][r]);
        }
    }
}

// ---- SPMM with LDS accumulators: 1 block per 128-row bucket ---------------
// CH=128: acc column layout permuted (ch 2l -> col l, ch 2l+1 -> col 64+l) so
// ds_add addresses are rl*128+lane => 2-way bank aliasing (free).
template <int CH, bool RELU>
__global__ __launch_bounds__(1024) void spmm_lds(const int* __restrict__ boff,
                                                 const int2* __restrict__ epk,
                                                 const unsigned short* __restrict__ yb,
                                                 const float* __restrict__ bias,
                                                 void* __restrict__ outp, int N) {
    __shared__ float accf[128 * CH];
    const int tid = threadIdx.x;
    const int b = blockIdx.x;
    for (int i = tid; i < 128 * CH; i += 1024) accf[i] = 0.f;
    __syncthreads();
    const int s = boff[b], e = boff[b + 1];
    const int wid = tid >> 6, lane = tid & 63;

    for (int bb = s + wid * 64; bb < e; bb += 1024) {
        const int idx = bb + lane;
        int2 pk = (idx < e) ? epk[idx] : make_int2(0, 0);
        const int cnt = min(64, e - bb);
        int px = __shfl(pk.x, 0, 64), pv = __shfl(pk.y, 0, 64);
        unsigned u = 0;
        unsigned short us = 0;
        if (CH == 128)
            u = ((const unsigned*)yb)[((size_t)(px & 0x1FFFF)) * 64 + lane];
        else
            us = yb[((size_t)(px & 0x1FFFF)) * 64 + lane];
        for (int j = 0; j < cnt; ++j) {
            int pxn = 0, pvn = 0;
            unsigned un = 0;
            unsigned short usn = 0;
            if (j + 1 < cnt) {
                pxn = __shfl(pk.x, j + 1, 64);
                pvn = __shfl(pk.y, j + 1, 64);
                if (CH == 128)
                    un = ((const unsigned*)yb)[((size_t)(pxn & 0x1FFFF)) * 64 + lane];
                else
                    usn = yb[((size_t)(pxn & 0x1FFFF)) * 64 + lane];
            }
            const float vv = __int_as_float(pv);
            const int rl = px >> 17;
            if (CH == 128) {
                float fx = __uint_as_float(u << 16);
                float fy = __uint_as_float(u & 0xffff0000u);
                atomicAdd(&accf[rl * 128 + lane], vv * fx);
                atomicAdd(&accf[rl * 128 + 64 + lane], vv * fy);
            } else {
                float f0 = __uint_as_float(((unsigned)us) << 16);
                atomicAdd(&accf[rl * 64 + lane], vv * f0);
            }
            px = pxn; pv = pvn; u = un; us = usn;
        }
    }
    __syncthreads();

    const int r0 = b * 128;
    if (CH == 128) {
        unsigned* o = (unsigned*)outp;
        for (int p = tid; p < 128 * 64; p += 1024) {
            int row = p >> 6, cp = p & 63;
            if (r0 + row < N) {
                float2 bv = ((const float2*)bias)[cp];
                float f0 = accf[row * 128 + cp] + bv.x;        // ch 2cp
                float f1 = accf[row * 128 + 64 + cp] + bv.y;   // ch 2cp+1
                if (RELU) { f0 = fmaxf(f0, 0.f); f1 = fmaxf(f1, 0.f); }
                o[(size_t)(r0 + row) * 64 + cp] = ((unsigned)f2bf(f1) << 16) | f2bf(f0);
            }
        }
    } else {
        float* o = (float*)outp;
        for (int p = tid; p < 128 * 64; p += 1024) {
            int row = p >> 6, ch = p & 63;
            if (r0 + row < N) o[(size_t)(r0 + row) * 64 + ch] = accf[row * 64 + ch] + bias[ch];
        }
    }
}

// ---------------------------------------------------------------------------
extern "C" void kernel_launch(void* const* d_in, const int* in_sizes, int n_in,
                              void* d_out, int out_size, void* d_ws, size_t ws_size,
                              hipStream_t stream) {
    const float* x    = (const float*)d_in[0];
    const int*   arow = (const int*)d_in[1];
    const int*   acol = (const int*)d_in[2];
    const float* aval = (const float*)d_in[3];
    const float* w1   = (const float*)d_in[4];
    const float* b1   = (const float*)d_in[5];
    const float* w2   = (const float*)d_in[6];
    const float* b2   = (const float*)d_in[7];
    float*       out  = (float*)d_out;

    const int N = in_sizes[0] / 128;   // 100000
    const int E = in_sizes[1];         // 1600000
    const int B = (N + 127) >> 7;      // 782 buckets of 128 rows

    char* p = (char*)d_ws;
    auto alloc = [&](size_t bytes) {
        char* r = p;
        p += (bytes + 255) & ~(size_t)255;
        return r;
    };
    int*            counts  = (int*)alloc((size_t)MAXB * 4);
    int*            boff    = (int*)alloc((size_t)(MAXB + 1) * 4);
    int*            gcursor = (int*)alloc((size_t)MAXB * 4);
    int2*           epk     = (int2*)alloc((size_t)E * 8);
    unsigned short* w1T     = (unsigned short*)alloc(128 * 128 * 2);
    unsigned short* w2T     = (unsigned short*)alloc(64 * 128 * 2);
    unsigned short* y1b     = (unsigned short*)alloc((size_t)N * 128 * 2);
    unsigned short* h1b     = (unsigned short*)alloc((size_t)N * 128 * 2);
    unsigned short* y2b     = (unsigned short*)alloc((size_t)N * 64 * 2);

    // ---- bucket partition ----
    hipMemsetAsync(counts, 0, (size_t)MAXB * 4, stream);
    const int pb = (E + 4095) / 4096;  // 391
    hist_b<<<pb, 256, 0, stream>>>(arow, counts, E, B);
    scan_s<<<1, 256, 0, stream>>>(counts, boff, gcursor, B, E);
    partition_k<<<pb, 256, 0, stream>>>(arow, acol, aval, gcursor, epk, E, B);

    // ---- weight casts ----
    cast_transpose_w<<<(128 * 128 + 255) / 256, 256, 0, stream>>>(w1, w1T, 128, 128);
    cast_transpose_w<<<(128 * 64 + 255) / 256, 256, 0, stream>>>(w2, w2T, 128, 64);

    // ---- layer 1 ----
    const int gemm_blocks = (N + 63) / 64;
    gemm_mfma<128, true><<<gemm_blocks, 256, 0, stream>>>(x, w1T, y1b, N);
    spmm_lds<128, true><<<B, 1024, 0, stream>>>(boff, epk, y1b, b1, h1b, N);

    // ---- layer 2 ----
    gemm_mfma<64, false><<<gemm_blocks, 256, 0, stream>>>(h1b, w2T, y2b, N);
    spmm_lds<64, false><<<B, 1024, 0, stream>>>(boff, epk, y2b, b2, out, N);
}

// Round 4
// 324.652 us; speedup vs baseline: 6.9675x; 6.9675x over previous
//
#include <hip/hip_runtime.h>

// ---------------------------------------------------------------------------
// GCN: out = spmm(A, relu(spmm(A, x)@w1 + b1)) @ w2 + b2
// Reordered: y1 = x@w1 ; h1 = relu(spmm(y1)+b1) ; y2 = h1@w2 ; out = spmm(y2)+b2
// R4: two-pass edge sort (coarse bucket partition w/ LDS staging -> per-bucket
//     LDS counting sort) => row-sorted {col,val} + rowptr, all writes
//     coalesced. spmm: wave-per-row, 4 independent gathers in flight,
//     wave-uniform edge-record loads (no shfl, no LDS atomics).
// ---------------------------------------------------------------------------

typedef __bf16 v8bf __attribute__((ext_vector_type(8)));
typedef float  v4f  __attribute__((ext_vector_type(4)));

#define MAXB 800  // max buckets (N<=102400)

__device__ __forceinline__ unsigned short f2bf(float f) {
    unsigned u = __float_as_uint(f);
    unsigned r = u + 0x7fffu + ((u >> 16) & 1u);   // RNE
    return (unsigned short)(r >> 16);
}

// ---- bucket histogram (LDS-aggregated) ------------------------------------
__global__ __launch_bounds__(256) void hist_b(const int* __restrict__ arow,
                                              int* __restrict__ counts, int E, int B) {
    __shared__ int lh[MAXB];
    const int tid = threadIdx.x;
    for (int i = tid; i < B; i += 256) lh[i] = 0;
    __syncthreads();
    const int base = blockIdx.x * 4096;
#pragma unroll
    for (int j = 0; j < 16; ++j) {
        int i = base + j * 256 + tid;
        if (i < E) atomicAdd(&lh[arow[i] >> 7], 1);
    }
    __syncthreads();
    for (int i = tid; i < B; i += 256) {
        int c = lh[i];
        if (c) atomicAdd(&counts[i], c);
    }
}

// ---- single-block exclusive scan over bucket counts + init sentinels ------
__global__ __launch_bounds__(256) void scan_s(const int* __restrict__ counts,
                                              int* __restrict__ boff,
                                              int* __restrict__ gcursor,
                                              int* __restrict__ rowptr,
                                              int2* __restrict__ epkS,
                                              int B, int E, int N) {
    __shared__ int lds[256];
    const int t = threadIdx.x;
    const int b0 = t * 4;
    int v[4];
    int s = 0;
#pragma unroll
    for (int j = 0; j < 4; ++j) {
        v[j] = (b0 + j < B) ? counts[b0 + j] : 0;
        s += v[j];
    }
    lds[t] = s;
    __syncthreads();
    for (int off = 1; off < 256; off <<= 1) {
        int tmp = 0;
        if (t >= off) tmp = lds[t - off];
        __syncthreads();
        if (t >= off) lds[t] += tmp;
        __syncthreads();
    }
    int run = (t > 0) ? lds[t - 1] : 0;
#pragma unroll
    for (int j = 0; j < 4; ++j) {
        if (b0 + j < B) {
            boff[b0 + j] = run;
            gcursor[b0 + j] = run;
        }
        run += v[j];
    }
    if (t == 255) {
        boff[B] = E;
        rowptr[N] = E;
        epkS[E] = make_int2(0, 0);      // sentinels for spmm 4-wide overread
        epkS[E + 1] = make_int2(0, 0);
        epkS[E + 2] = make_int2(0, 0);
    }
}

// ---- pass 1: bucket-order edges with LDS staging (coalesced out) ----------
__global__ __launch_bounds__(256) void partition_k(const int* __restrict__ arow,
                                                   const int* __restrict__ acol,
                                                   const float* __restrict__ aval,
                                                   int* __restrict__ gcursor,
                                                   int2* __restrict__ epk, int E, int B) {
    __shared__ int2 ldata[4096];
    __shared__ int ldest[4096];
    __shared__ int lhist[MAXB];
    __shared__ int lscan[MAXB];
    __shared__ int ldelta[MAXB];
    __shared__ int lcur[MAXB];
    __shared__ int stmp[256];
    const int tid = threadIdx.x;
    const int base = blockIdx.x * 4096;
    const int cnt = min(4096, E - base);

    for (int i = tid; i < MAXB; i += 256) {
        lhist[i] = 0;
        lcur[i] = 0;
    }
    __syncthreads();

    int rr[16];
#pragma unroll
    for (int j = 0; j < 16; ++j) {
        int i = base + j * 256 + tid;
        rr[j] = (i < E) ? arow[i] : -1;
        if (rr[j] >= 0) atomicAdd(&lhist[rr[j] >> 7], 1);
    }
    __syncthreads();

    const int b0 = tid * 4;
    int v[4];
    int s = 0;
#pragma unroll
    for (int j = 0; j < 4; ++j) {
        v[j] = (b0 + j < MAXB) ? lhist[b0 + j] : 0;
        s += v[j];
    }
    stmp[tid] = s;
    __syncthreads();
    for (int off = 1; off < 256; off <<= 1) {
        int tmp = 0;
        if (tid >= off) tmp = stmp[tid - off];
        __syncthreads();
        if (tid >= off) stmp[tid] += tmp;
        __syncthreads();
    }
    int run = (tid > 0) ? stmp[tid - 1] : 0;
#pragma unroll
    for (int j = 0; j < 4; ++j) {
        if (b0 + j < MAXB) lscan[b0 + j] = run;
        run += v[j];
    }
    __syncthreads();

    for (int b = tid; b < B; b += 256) {
        int c = lhist[b];
        if (c) ldelta[b] = atomicAdd(&gcursor[b], c) - lscan[b];
    }
    __syncthreads();

#pragma unroll
    for (int j = 0; j < 16; ++j) {
        int i = base + j * 256 + tid;
        if (i < E) {
            int r = rr[j];
            int b = r >> 7;
            int lp = atomicAdd(&lcur[b], 1);
            int slot = lscan[b] + lp;
            int pk = acol[i] | ((r & 127) << 17);
            ldata[slot] = make_int2(pk, __float_as_int(aval[i]));
            ldest[slot] = ldelta[b] + slot;
        }
    }
    __syncthreads();

    for (int s2 = tid; s2 < cnt; s2 += 256) epk[ldest[s2]] = ldata[s2];
}

// ---- pass 2: per-bucket LDS counting sort by local row + rowptr emit ------
__global__ __launch_bounds__(256) void bucket_sort(const int* __restrict__ boff,
                                                   const int2* __restrict__ epk,
                                                   int2* __restrict__ epkS,
                                                   int* __restrict__ rowptr, int N) {
    __shared__ int2 sorted[4096];
    __shared__ int sc[128];
    __shared__ int lcur[128];
    const int tid = threadIdx.x;
    const int b = blockIdx.x;
    const int s = boff[b], e = boff[b + 1];
    const int cnt = min(e - s, 4096);
    if (tid < 128) sc[tid] = 0;
    __syncthreads();
    // histogram local rows
    for (int i = s + tid; i < e; i += 256) {
        int rl = (epk[i].x >> 17) & 127;
        atomicAdd(&sc[rl], 1);
    }
    __syncthreads();
    int hv = (tid < 128) ? sc[tid] : 0;
    // inclusive Hillis-Steele over 128
    for (int off = 1; off < 128; off <<= 1) {
        int add = 0;
        if (tid < 128 && tid >= off) add = sc[tid - off];
        __syncthreads();
        if (tid < 128 && tid >= off) sc[tid] += add;
        __syncthreads();
    }
    if (tid < 128) {
        int ex = sc[tid] - hv;  // exclusive
        lcur[tid] = ex;
        int r = b * 128 + tid;
        if (r < N) rowptr[r] = s + ex;
    }
    __syncthreads();
    // scatter into LDS, stripping the rl tag
    for (int i = s + tid; i < e; i += 256) {
        int2 p = epk[i];
        int rl = (p.x >> 17) & 127;
        int slot = atomicAdd(&lcur[rl], 1);
        if (slot < 4096) sorted[slot] = make_int2(p.x & 0x1FFFF, p.y);
    }
    __syncthreads();
    // coalesced copy-out
    for (int i = tid; i < cnt; i += 256) epkS[s + i] = sorted[i];
}

// ---- cast + transpose weights: w[K][NC] fp32 -> wT[NC][K] bf16 ------------
__global__ void cast_transpose_w(const float* __restrict__ w, unsigned short* __restrict__ wT,
                                 int K, int NC) {
    int i = blockIdx.x * blockDim.x + threadIdx.x;
    if (i < K * NC) {
        int k = i / NC, n = i - k * NC;
        wT[n * K + k] = f2bf(w[i]);
    }
}

// ---- MFMA GEMM: y_bf16[M x NC] = A[M x 128] @ W[128 x NC] -----------------
template <int NC, bool AF32>
__global__ __launch_bounds__(256) void gemm_mfma(const void* __restrict__ A,
                                                 const unsigned short* __restrict__ wT,
                                                 unsigned short* __restrict__ y, int M) {
    constexpr int KP = 136;
    constexpr int NT = NC / 16;
    __shared__ unsigned short wl[NC * KP];
    const int tid = threadIdx.x;
    for (int idx = tid; idx < NC * 16; idx += 256) {
        int n = idx >> 4, kc = idx & 15;
        *(uint4*)&wl[n * KP + kc * 8] = *(const uint4*)&wT[n * 128 + kc * 8];
    }
    __syncthreads();

    const int wave = tid >> 6;
    const int lane = tid & 63;
    const int m = lane & 15;
    const int q = lane >> 4;
    const int rowbase = blockIdx.x * 64 + wave * 16;
    const int rowc = min(rowbase + m, M - 1);

    v4f acc[NT] = {};
    union LU { uint4 qv; v8bf b; };

#pragma unroll
    for (int ks = 0; ks < 4; ++ks) {
        const int k0 = ks * 32 + q * 8;
        v8bf a;
        if (AF32) {
            const float* Ap = (const float*)A + (size_t)rowc * 128 + k0;
            float4 f0 = *(const float4*)Ap;
            float4 f1 = *(const float4*)(Ap + 4);
            union { unsigned short s[8]; v8bf b; } cv;
            cv.s[0] = f2bf(f0.x); cv.s[1] = f2bf(f0.y);
            cv.s[2] = f2bf(f0.z); cv.s[3] = f2bf(f0.w);
            cv.s[4] = f2bf(f1.x); cv.s[5] = f2bf(f1.y);
            cv.s[6] = f2bf(f1.z); cv.s[7] = f2bf(f1.w);
            a = cv.b;
        } else {
            LU lu;
            lu.qv = *(const uint4*)((const unsigned short*)A + (size_t)rowc * 128 + k0);
            a = lu.b;
        }
#pragma unroll
        for (int nt = 0; nt < NT; ++nt) {
            v8bf b = *(const v8bf*)&wl[(nt * 16 + m) * KP + k0];
            acc[nt] = __builtin_amdgcn_mfma_f32_16x16x32_bf16(a, b, acc[nt], 0, 0, 0);
        }
    }
#pragma unroll
    for (int nt = 0; nt < NT; ++nt) {
#pragma unroll
        for (int r = 0; r < 4; ++r) {
            int orow = rowbase + q * 4 + r;
            if (orow < M) y[(size_t)orow * NC + nt * 16 + m] = f2bf(acc[nt][r]);
        }
    }
}

// ---- SPMM: wave per row, 4 gathers in flight, no shfl ---------------------
// CH=128: lane covers ch {2l,2l+1} (one dword). CH=64: lane covers ch l.
template <int CH, bool RELU, bool OUT_BF16>
__global__ __launch_bounds__(256) void spmm_v2(const int* __restrict__ rowptr,
                                               const int2* __restrict__ ep,
                                               const unsigned short* __restrict__ yb,
                                               const float* __restrict__ bias,
                                               void* __restrict__ outp, int N) {
    const int row = (blockIdx.x * 256 + threadIdx.x) >> 6;
    const int lane = threadIdx.x & 63;
    if (row >= N) return;
    const int s = rowptr[row], e = rowptr[row + 1];
    float accx = 0.f, accy = 0.f;
    for (int j = s; j < e; j += 4) {
        // edge records: wave-uniform loads (overread masked by val=0; 3
        // sentinel records exist past E)
        int2 e0 = ep[j];
        int2 e1 = ep[j + 1];
        int2 e2 = ep[j + 2];
        int2 e3 = ep[j + 3];
        float v0 = __int_as_float(e0.y);
        float v1 = (j + 1 < e) ? __int_as_float(e1.y) : 0.f;
        float v2 = (j + 2 < e) ? __int_as_float(e2.y) : 0.f;
        float v3 = (j + 3 < e) ? __int_as_float(e3.y) : 0.f;
        if (CH == 128) {
            const unsigned* y32 = (const unsigned*)yb;
            unsigned u0 = y32[(size_t)e0.x * 64 + lane];
            unsigned u1 = y32[(size_t)e1.x * 64 + lane];
            unsigned u2 = y32[(size_t)e2.x * 64 + lane];
            unsigned u3 = y32[(size_t)e3.x * 64 + lane];
            accx += v0 * __uint_as_float(u0 << 16);
            accy += v0 * __uint_as_float(u0 & 0xffff0000u);
            accx += v1 * __uint_as_float(u1 << 16);
            accy += v1 * __uint_as_float(u1 & 0xffff0000u);
            accx += v2 * __uint_as_float(u2 << 16);
            accy += v2 * __uint_as_float(u2 & 0xffff0000u);
            accx += v3 * __uint_as_float(u3 << 16);
            accy += v3 * __uint_as_float(u3 & 0xffff0000u);
        } else {
            unsigned u0 = yb[(size_t)e0.x * 64 + lane];
            unsigned u1 = yb[(size_t)e1.x * 64 + lane];
            unsigned u2 = yb[(size_t)e2.x * 64 + lane];
            unsigned u3 = yb[(size_t)e3.x * 64 + lane];
            accx += v0 * __uint_as_float(u0 << 16);
            accx += v1 * __uint_as_float(u1 << 16);
            accx += v2 * __uint_as_float(u2 << 16);
            accx += v3 * __uint_as_float(u3 << 16);
        }
    }
    if (CH == 128) {
        float2 bv = ((const float2*)bias)[lane];
        accx += bv.x;
        accy += bv.y;
        if (RELU) { accx = fmaxf(accx, 0.f); accy = fmaxf(accy, 0.f); }
        if (OUT_BF16) {
            unsigned pk = ((unsigned)f2bf(accy) << 16) | f2bf(accx);
            ((unsigned*)outp)[(size_t)row * 64 + lane] = pk;
        } else {
            float2 o; o.x = accx; o.y = accy;
            ((float2*)outp)[(size_t)row * 64 + lane] = o;
        }
    } else {
        accx += bias[lane];
        if (RELU) accx = fmaxf(accx, 0.f);
        if (OUT_BF16) {
            ((unsigned short*)outp)[(size_t)row * 64 + lane] = f2bf(accx);
        } else {
            ((float*)outp)[(size_t)row * 64 + lane] = accx;
        }
    }
}

// ---------------------------------------------------------------------------
extern "C" void kernel_launch(void* const* d_in, const int* in_sizes, int n_in,
                              void* d_out, int out_size, void* d_ws, size_t ws_size,
                              hipStream_t stream) {
    const float* x    = (const float*)d_in[0];
    const int*   arow = (const int*)d_in[1];
    const int*   acol = (const int*)d_in[2];
    const float* aval = (const float*)d_in[3];
    const float* w1   = (const float*)d_in[4];
    const float* b1   = (const float*)d_in[5];
    const float* w2   = (const float*)d_in[6];
    const float* b2   = (const float*)d_in[7];
    float*       out  = (float*)d_out;

    const int N = in_sizes[0] / 128;   // 100000
    const int E = in_sizes[1];         // 1600000
    const int B = (N + 127) >> 7;      // 782 buckets of 128 rows

    char* p = (char*)d_ws;
    auto alloc = [&](size_t bytes) {
        char* r = p;
        p += (bytes + 255) & ~(size_t)255;
        return r;
    };
    int*            counts  = (int*)alloc((size_t)MAXB * 4);
    int*            boff    = (int*)alloc((size_t)(MAXB + 1) * 4);
    int*            gcursor = (int*)alloc((size_t)MAXB * 4);
    int*            rowptr  = (int*)alloc((size_t)(N + 1) * 4);
    int2*           epkS    = (int2*)alloc((size_t)(E + 4) * 8);
    unsigned short* w1T     = (unsigned short*)alloc(128 * 128 * 2);
    unsigned short* w2T     = (unsigned short*)alloc(64 * 128 * 2);
    unsigned short* y1b     = (unsigned short*)alloc((size_t)N * 128 * 2);
    unsigned short* h1b     = (unsigned short*)alloc((size_t)N * 128 * 2);
    unsigned short* y2b     = (unsigned short*)alloc((size_t)N * 64 * 2);
    // pass-1 output aliases h1b (dead until spmm1, which runs after sort)
    int2*           epk     = (int2*)h1b;

    // ---- edge sort (two-pass) ----
    hipMemsetAsync(counts, 0, (size_t)MAXB * 4, stream);
    const int pb = (E + 4095) / 4096;  // 391
    hist_b<<<pb, 256, 0, stream>>>(arow, counts, E, B);
    scan_s<<<1, 256, 0, stream>>>(counts, boff, gcursor, rowptr, epkS, B, E, N);
    partition_k<<<pb, 256, 0, stream>>>(arow, acol, aval, gcursor, epk, E, B);
    bucket_sort<<<B, 256, 0, stream>>>(boff, epk, epkS, rowptr, N);

    // ---- weight casts ----
    cast_transpose_w<<<(128 * 128 + 255) / 256, 256, 0, stream>>>(w1, w1T, 128, 128);
    cast_transpose_w<<<(128 * 64 + 255) / 256, 256, 0, stream>>>(w2, w2T, 128, 64);

    // ---- layer 1 ----
    const int gemm_blocks = (N + 63) / 64;
    gemm_mfma<128, true><<<gemm_blocks, 256, 0, stream>>>(x, w1T, y1b, N);
    const int spmm_blocks = (N + 3) / 4;
    spmm_v2<128, true, true><<<spmm_blocks, 256, 0, stream>>>(rowptr, epkS, y1b, b1, h1b, N);

    // ---- layer 2 ----
    gemm_mfma<64, false><<<gemm_blocks, 256, 0, stream>>>(h1b, w2T, y2b, N);
    spmm_v2<64, false, false><<<spmm_blocks, 256, 0, stream>>>(rowptr, epkS, y2b, b2, out, N);
}

// Round 5
// 321.426 us; speedup vs baseline: 7.0374x; 1.0100x over previous
//
#include <hip/hip_runtime.h>

// ---------------------------------------------------------------------------
// GCN: out = spmm(A, relu(spmm(A, x)@w1 + b1)) @ w2 + b2
// Reordered: y1 = x@w1 ; h1 = relu(spmm(y1)+b1) ; y2 = h1@w2 ; out = spmm(y2)+b2
// R5: 8-deep gather pipelining + edge-record prefetch in spmm; half-wave
//     2-edges-per-instruction scheme for CH=64 spmm; block-range fusion of
//     bucket_sort + gemm1 (independent, same LDS budget); prep kernel fuses
//     weight casts + zero-init + sentinels. 8 dispatches total.
// ---------------------------------------------------------------------------

typedef __bf16 v8bf __attribute__((ext_vector_type(8)));
typedef float  v4f  __attribute__((ext_vector_type(4)));

#define MAXB 800  // max buckets (N<=102400)

__device__ __forceinline__ unsigned short f2bf(float f) {
    unsigned u = __float_as_uint(f);
    unsigned r = u + 0x7fffu + ((u >> 16) & 1u);   // RNE
    return (unsigned short)(r >> 16);
}

// ---- prep: weight cast/transpose + zero counts + sentinels + rowptr[N] ----
__global__ __launch_bounds__(256) void prep_k(const float* __restrict__ w1,
                                              const float* __restrict__ w2,
                                              unsigned short* __restrict__ w1T,
                                              unsigned short* __restrict__ w2T,
                                              int* __restrict__ counts,
                                              int* __restrict__ rowptr,
                                              int2* __restrict__ epkS, int E, int N) {
    int i = blockIdx.x * 256 + threadIdx.x;
    if (i < 16384) {                       // w1T[n*128+k] = w1[k*128+n]
        int n = i >> 7, k = i & 127;
        w1T[i] = f2bf(w1[k * 128 + n]);
    } else if (i < 24576) {                // w2T[n*128+k] = w2[k*64+n]
        int i2 = i - 16384;
        int n = i2 >> 7, k = i2 & 127;
        w2T[i2] = f2bf(w2[k * 64 + n]);
    } else if (i < 24576 + MAXB) {
        counts[i - 24576] = 0;
    } else if (i < 24576 + MAXB + 32) {    // sentinels for spmm overread
        epkS[E + (i - 24576 - MAXB)] = make_int2(0, 0);
    } else if (i == 24576 + MAXB + 32) {
        rowptr[N] = E;
    }
}

// ---- bucket histogram (LDS-aggregated) ------------------------------------
__global__ __launch_bounds__(256) void hist_b(const int* __restrict__ arow,
                                              int* __restrict__ counts, int E, int B) {
    __shared__ int lh[MAXB];
    const int tid = threadIdx.x;
    for (int i = tid; i < B; i += 256) lh[i] = 0;
    __syncthreads();
    const int base = blockIdx.x * 4096;
#pragma unroll
    for (int j = 0; j < 16; ++j) {
        int i = base + j * 256 + tid;
        if (i < E) atomicAdd(&lh[arow[i] >> 7], 1);
    }
    __syncthreads();
    for (int i = tid; i < B; i += 256) {
        int c = lh[i];
        if (c) atomicAdd(&counts[i], c);
    }
}

// ---- single-block exclusive scan over bucket counts -----------------------
__global__ __launch_bounds__(256) void scan_s(const int* __restrict__ counts,
                                              int* __restrict__ boff,
                                              int* __restrict__ gcursor, int B, int E) {
    __shared__ int lds[256];
    const int t = threadIdx.x;
    const int b0 = t * 4;
    int v[4];
    int s = 0;
#pragma unroll
    for (int j = 0; j < 4; ++j) {
        v[j] = (b0 + j < B) ? counts[b0 + j] : 0;
        s += v[j];
    }
    lds[t] = s;
    __syncthreads();
    for (int off = 1; off < 256; off <<= 1) {
        int tmp = 0;
        if (t >= off) tmp = lds[t - off];
        __syncthreads();
        if (t >= off) lds[t] += tmp;
        __syncthreads();
    }
    int run = (t > 0) ? lds[t - 1] : 0;
#pragma unroll
    for (int j = 0; j < 4; ++j) {
        if (b0 + j < B) {
            boff[b0 + j] = run;
            gcursor[b0 + j] = run;
        }
        run += v[j];
    }
    if (t == 255) boff[B] = E;
}

// ---- pass 1: bucket-order edges with LDS staging (coalesced out) ----------
__global__ __launch_bounds__(256) void partition_k(const int* __restrict__ arow,
                                                   const int* __restrict__ acol,
                                                   const float* __restrict__ aval,
                                                   int* __restrict__ gcursor,
                                                   int2* __restrict__ epk, int E, int B) {
    __shared__ int2 ldata[4096];
    __shared__ int ldest[4096];
    __shared__ int lhist[MAXB];
    __shared__ int lscan[MAXB];
    __shared__ int ldelta[MAXB];
    __shared__ int lcur[MAXB];
    __shared__ int stmp[256];
    const int tid = threadIdx.x;
    const int base = blockIdx.x * 4096;
    const int cnt = min(4096, E - base);

    for (int i = tid; i < MAXB; i += 256) {
        lhist[i] = 0;
        lcur[i] = 0;
    }
    __syncthreads();

    int rr[16];
#pragma unroll
    for (int j = 0; j < 16; ++j) {
        int i = base + j * 256 + tid;
        rr[j] = (i < E) ? arow[i] : -1;
        if (rr[j] >= 0) atomicAdd(&lhist[rr[j] >> 7], 1);
    }
    __syncthreads();

    const int b0 = tid * 4;
    int v[4];
    int s = 0;
#pragma unroll
    for (int j = 0; j < 4; ++j) {
        v[j] = (b0 + j < MAXB) ? lhist[b0 + j] : 0;
        s += v[j];
    }
    stmp[tid] = s;
    __syncthreads();
    for (int off = 1; off < 256; off <<= 1) {
        int tmp = 0;
        if (tid >= off) tmp = stmp[tid - off];
        __syncthreads();
        if (tid >= off) stmp[tid] += tmp;
        __syncthreads();
    }
    int run = (tid > 0) ? stmp[tid - 1] : 0;
#pragma unroll
    for (int j = 0; j < 4; ++j) {
        if (b0 + j < MAXB) lscan[b0 + j] = run;
        run += v[j];
    }
    __syncthreads();

    for (int b = tid; b < B; b += 256) {
        int c = lhist[b];
        if (c) ldelta[b] = atomicAdd(&gcursor[b], c) - lscan[b];
    }
    __syncthreads();

#pragma unroll
    for (int j = 0; j < 16; ++j) {
        int i = base + j * 256 + tid;
        if (i < E) {
            int r = rr[j];
            int b = r >> 7;
            int lp = atomicAdd(&lcur[b], 1);
            int slot = lscan[b] + lp;
            int pk = acol[i] | ((r & 127) << 17);
            ldata[slot] = make_int2(pk, __float_as_int(aval[i]));
            ldest[slot] = ldelta[b] + slot;
        }
    }
    __syncthreads();

    for (int s2 = tid; s2 < cnt; s2 += 256) epk[ldest[s2]] = ldata[s2];
}

// ---- MFMA GEMM body: y_bf16[M x NC] = A[M x 128] @ W[128 x NC] ------------
template <int NC, bool AF32>
__device__ __forceinline__ void gemm_body(const void* __restrict__ A,
                                          const unsigned short* __restrict__ wT,
                                          unsigned short* __restrict__ y, int M,
                                          int bid, char* smem) {
    constexpr int KP = 136;
    constexpr int NT = NC / 16;
    unsigned short* wl = (unsigned short*)smem;
    const int tid = threadIdx.x;
    for (int idx = tid; idx < NC * 16; idx += 256) {
        int n = idx >> 4, kc = idx & 15;
        *(uint4*)&wl[n * KP + kc * 8] = *(const uint4*)&wT[n * 128 + kc * 8];
    }
    __syncthreads();

    const int wave = tid >> 6;
    const int lane = tid & 63;
    const int m = lane & 15;
    const int q = lane >> 4;
    const int rowbase = bid * 64 + wave * 16;
    const int rowc = min(rowbase + m, M - 1);

    v4f acc[NT] = {};
    union LU { uint4 qv; v8bf b; };

#pragma unroll
    for (int ks = 0; ks < 4; ++ks) {
        const int k0 = ks * 32 + q * 8;
        v8bf a;
        if (AF32) {
            const float* Ap = (const float*)A + (size_t)rowc * 128 + k0;
            float4 f0 = *(const float4*)Ap;
            float4 f1 = *(const float4*)(Ap + 4);
            union { unsigned short s[8]; v8bf b; } cv;
            cv.s[0] = f2bf(f0.x); cv.s[1] = f2bf(f0.y);
            cv.s[2] = f2bf(f0.z); cv.s[3] = f2bf(f0.w);
            cv.s[4] = f2bf(f1.x); cv.s[5] = f2bf(f1.y);
            cv.s[6] = f2bf(f1.z); cv.s[7] = f2bf(f1.w);
            a = cv.b;
        } else {
            LU lu;
            lu.qv = *(const uint4*)((const unsigned short*)A + (size_t)rowc * 128 + k0);
            a = lu.b;
        }
#pragma unroll
        for (int nt = 0; nt < NT; ++nt) {
            v8bf b = *(const v8bf*)&wl[(nt * 16 + m) * KP + k0];
            acc[nt] = __builtin_amdgcn_mfma_f32_16x16x32_bf16(a, b, acc[nt], 0, 0, 0);
        }
    }
#pragma unroll
    for (int nt = 0; nt < NT; ++nt) {
#pragma unroll
        for (int r = 0; r < 4; ++r) {
            int orow = rowbase + q * 4 + r;
            if (orow < M) y[(size_t)orow * NC + nt * 16 + m] = f2bf(acc[nt][r]);
        }
    }
}

// ---- fused: bucket_sort (blocks [0,B)) || gemm1 (blocks [B, B+gb)) --------
__global__ __launch_bounds__(256) void sort_gemm1(const int* __restrict__ boff,
                                                  const int2* __restrict__ epk,
                                                  int2* __restrict__ epkS,
                                                  int* __restrict__ rowptr, int N, int B,
                                                  const float* __restrict__ x,
                                                  const unsigned short* __restrict__ w1T,
                                                  unsigned short* __restrict__ y1b) {
    __shared__ __align__(16) char smem[34816];
    const int tid = threadIdx.x;
    if (blockIdx.x >= B) {
        gemm_body<128, true>(x, w1T, y1b, N, blockIdx.x - B, smem);
        return;
    }
    // ---- bucket_sort: per-bucket LDS counting sort by local row ----
    int2* sorted = (int2*)smem;                  // 4096 * 8 = 32768
    int*  sc     = (int*)(smem + 32768);         // 128 * 4
    int*  lcur   = (int*)(smem + 32768 + 512);   // 128 * 4
    const int b = blockIdx.x;
    const int s = boff[b], e = boff[b + 1];
    const int cnt = min(e - s, 4096);
    if (tid < 128) sc[tid] = 0;
    __syncthreads();
    for (int i = s + tid; i < e; i += 256) {
        int rl = (epk[i].x >> 17) & 127;
        atomicAdd(&sc[rl], 1);
    }
    __syncthreads();
    int hv = (tid < 128) ? sc[tid] : 0;
    for (int off = 1; off < 128; off <<= 1) {
        int add = 0;
        if (tid < 128 && tid >= off) add = sc[tid - off];
        __syncthreads();
        if (tid < 128 && tid >= off) sc[tid] += add;
        __syncthreads();
    }
    if (tid < 128) {
        int ex = sc[tid] - hv;  // exclusive
        lcur[tid] = ex;
        int r = b * 128 + tid;
        if (r < N) rowptr[r] = s + ex;
    }
    __syncthreads();
    for (int i = s + tid; i < e; i += 256) {
        int2 p = epk[i];
        int rl = (p.x >> 17) & 127;
        int slot = atomicAdd(&lcur[rl], 1);
        if (slot < 4096) sorted[slot] = make_int2(p.x & 0x1FFFF, p.y);
    }
    __syncthreads();
    for (int i = tid; i < cnt; i += 256) epkS[s + i] = sorted[i];
}

// ---- standalone gemm2 -----------------------------------------------------
__global__ __launch_bounds__(256) void gemm2_k(const unsigned short* __restrict__ h1b,
                                               const unsigned short* __restrict__ w2T,
                                               unsigned short* __restrict__ y2b, int M) {
    __shared__ __align__(16) char smem[64 * 136 * 2];
    gemm_body<64, false>(h1b, w2T, y2b, M, blockIdx.x, smem);
}

// ---- SPMM CH=128: wave/row, 8 gathers in flight + record prefetch ---------
// lane covers ch {2l, 2l+1} (one dword/edge). Output bf16 packed + relu.
__global__ __launch_bounds__(256) void spmm128(const int* __restrict__ rowptr,
                                               const int2* __restrict__ ep,
                                               const unsigned short* __restrict__ yb,
                                               const float* __restrict__ bias,
                                               unsigned* __restrict__ outp, int N) {
    const int row = (blockIdx.x * 256 + threadIdx.x) >> 6;
    const int lane = threadIdx.x & 63;
    if (row >= N) return;
    const int s = rowptr[row], e = rowptr[row + 1];
    const unsigned* y32 = (const unsigned*)yb;
    float accx = 0.f, accy = 0.f;
    int2 cur[8];
#pragma unroll
    for (int k = 0; k < 8; ++k) cur[k] = ep[s + k];
    for (int j = s; j < e; j += 8) {
        int2 nxt[8];
#pragma unroll
        for (int k = 0; k < 8; ++k) nxt[k] = ep[j + 8 + k];
#pragma unroll
        for (int k = 0; k < 8; ++k) {
            float v = (j + k < e) ? __int_as_float(cur[k].y) : 0.f;
            unsigned u = y32[(size_t)cur[k].x * 64 + lane];
            accx += v * __uint_as_float(u << 16);
            accy += v * __uint_as_float(u & 0xffff0000u);
        }
#pragma unroll
        for (int k = 0; k < 8; ++k) cur[k] = nxt[k];
    }
    float2 bv = ((const float2*)bias)[lane];
    accx += bv.x;
    accy += bv.y;
    accx = fmaxf(accx, 0.f);
    accy = fmaxf(accy, 0.f);
    outp[(size_t)row * 64 + lane] = ((unsigned)f2bf(accy) << 16) | f2bf(accx);
}

// ---- SPMM CH=64: wave/row, half-wave handles alternating edges ------------
// lanes 0-31: edges j+2k ; lanes 32-63: edges j+2k+1. Each lane: one dword =
// ch {2sl, 2sl+1}. Final shfl_xor(32) combine; lanes<32 store fp32 float2.
__global__ __launch_bounds__(256) void spmm64(const int* __restrict__ rowptr,
                                              const int2* __restrict__ ep,
                                              const unsigned short* __restrict__ yb,
                                              const float* __restrict__ bias,
                                              float2* __restrict__ outp, int N) {
    const int row = (blockIdx.x * 256 + threadIdx.x) >> 6;
    const int lane = threadIdx.x & 63;
    if (row >= N) return;
    const int half = lane >> 5;
    const int sl = lane & 31;
    const int s = rowptr[row], e = rowptr[row + 1];
    const unsigned* y32 = (const unsigned*)yb;
    float accx = 0.f, accy = 0.f;
    int2 cur[8];
#pragma unroll
    for (int k = 0; k < 8; ++k) cur[k] = ep[s + 2 * k + half];
    for (int j = s; j < e; j += 16) {
        int2 nxt[8];
#pragma unroll
        for (int k = 0; k < 8; ++k) nxt[k] = ep[j + 16 + 2 * k + half];
#pragma unroll
        for (int k = 0; k < 8; ++k) {
            float v = (j + 2 * k + half < e) ? __int_as_float(cur[k].y) : 0.f;
            unsigned u = y32[(size_t)cur[k].x * 32 + sl];
            accx += v * __uint_as_float(u << 16);
            accy += v * __uint_as_float(u & 0xffff0000u);
        }
#pragma unroll
        for (int k = 0; k < 8; ++k) cur[k] = nxt[k];
    }
    accx += __shfl_xor(accx, 32, 64);
    accy += __shfl_xor(accy, 32, 64);
    if (sl == lane) {  // lanes 0-31
        float2 bv = ((const float2*)bias)[sl];
        float2 o;
        o.x = accx + bv.x;
        o.y = accy + bv.y;
        outp[(size_t)row * 32 + sl] = o;
    }
}

// ---------------------------------------------------------------------------
extern "C" void kernel_launch(void* const* d_in, const int* in_sizes, int n_in,
                              void* d_out, int out_size, void* d_ws, size_t ws_size,
                              hipStream_t stream) {
    const float* x    = (const float*)d_in[0];
    const int*   arow = (const int*)d_in[1];
    const int*   acol = (const int*)d_in[2];
    const float* aval = (const float*)d_in[3];
    const float* w1   = (const float*)d_in[4];
    const float* b1   = (const float*)d_in[5];
    const float* w2   = (const float*)d_in[6];
    const float* b2   = (const float*)d_in[7];
    float*       out  = (float*)d_out;

    const int N = in_sizes[0] / 128;   // 100000
    const int E = in_sizes[1];         // 1600000
    const int B = (N + 127) >> 7;      // 782 buckets of 128 rows

    char* p = (char*)d_ws;
    auto alloc = [&](size_t bytes) {
        char* r = p;
        p += (bytes + 255) & ~(size_t)255;
        return r;
    };
    int*            counts  = (int*)alloc((size_t)MAXB * 4);
    int*            boff    = (int*)alloc((size_t)(MAXB + 1) * 4);
    int*            gcursor = (int*)alloc((size_t)MAXB * 4);
    int*            rowptr  = (int*)alloc((size_t)(N + 1) * 4);
    int2*           epkS    = (int2*)alloc((size_t)(E + 32) * 8);
    unsigned short* w1T     = (unsigned short*)alloc(128 * 128 * 2);
    unsigned short* w2T     = (unsigned short*)alloc(64 * 128 * 2);
    unsigned short* y1b     = (unsigned short*)alloc((size_t)N * 128 * 2);
    unsigned short* h1b     = (unsigned short*)alloc((size_t)N * 128 * 2);
    unsigned short* y2b     = (unsigned short*)alloc((size_t)N * 64 * 2);
    // pass-1 output aliases h1b (dead until spmm1, which runs after sort)
    int2*           epk     = (int2*)h1b;

    const int gemm_blocks = (N + 63) / 64;   // 1563
    const int pb = (E + 4095) / 4096;        // 391

    // ---- prep (casts, zero counts, sentinels) ----
    prep_k<<<(24576 + MAXB + 33 + 255) / 256, 256, 0, stream>>>(
        w1, w2, w1T, w2T, counts, rowptr, epkS, E, N);
    // ---- edge sort pass 1 ----
    hist_b<<<pb, 256, 0, stream>>>(arow, counts, E, B);
    scan_s<<<1, 256, 0, stream>>>(counts, boff, gcursor, B, E);
    partition_k<<<pb, 256, 0, stream>>>(arow, acol, aval, gcursor, epk, E, B);
    // ---- fused: edge sort pass 2 || gemm1 ----
    sort_gemm1<<<B + gemm_blocks, 256, 0, stream>>>(boff, epk, epkS, rowptr, N, B,
                                                    x, w1T, y1b);
    // ---- spmm1 (relu, bf16 out) ----
    const int spmm_blocks = (N + 3) / 4;
    spmm128<<<spmm_blocks, 256, 0, stream>>>(rowptr, epkS, y1b, b1, (unsigned*)h1b, N);
    // ---- gemm2 ----
    gemm2_k<<<gemm_blocks, 256, 0, stream>>>(h1b, w2T, y2b, N);
    // ---- spmm2 (fp32 out) ----
    spmm64<<<spmm_blocks, 256, 0, stream>>>(rowptr, epkS, y2b, b2, (float2*)out, N);
}

// Round 6
// 313.675 us; speedup vs baseline: 7.2113x; 1.0247x over previous
//
#include <hip/hip_runtime.h>

// ---------------------------------------------------------------------------
// GCN: out = spmm(A, relu(spmm(A, x)@w1 + b1)) @ w2 + b2
// Reordered: y1 = x@w1 ; h1 = relu(spmm(y1)+b1) ; y2 = h1@w2 ; out = spmm(y2)+b2
// R6: spmm1+gemm2 fused (h1 tile lives in LDS, never touches HBM); spmm2
//     reverted to full-wave-per-edge ushort gathers + 8-deep pipelining;
//     prep folded into hist. 7 dispatches.
// ---------------------------------------------------------------------------

typedef __bf16 v8bf __attribute__((ext_vector_type(8)));
typedef float  v4f  __attribute__((ext_vector_type(4)));

#define MAXB 800  // max buckets (N<=102400)

__device__ __forceinline__ unsigned short f2bf(float f) {
    unsigned u = __float_as_uint(f);
    unsigned r = u + 0x7fffu + ((u >> 16) & 1u);   // RNE
    return (unsigned short)(r >> 16);
}

// ---- hist + prep: bucket histogram, weight casts, sentinels ---------------
__global__ __launch_bounds__(256) void hist_prep(const int* __restrict__ arow,
                                                 int* __restrict__ counts, int E, int B,
                                                 const float* __restrict__ w1,
                                                 const float* __restrict__ w2,
                                                 unsigned short* __restrict__ w1T,
                                                 unsigned short* __restrict__ w2T,
                                                 int* __restrict__ rowptr,
                                                 int2* __restrict__ epkS, int N) {
    const int tid = threadIdx.x;
    // ---- prep slice (first ~100 blocks' threads) ----
    int gi = blockIdx.x * 256 + tid;
    if (gi < 16384) {                       // w1T[n*128+k] = w1[k*128+n]
        int n = gi >> 7, k = gi & 127;
        w1T[gi] = f2bf(w1[k * 128 + n]);
    } else if (gi < 24576) {                // w2T[n*128+k] = w2[k*64+n]
        int i2 = gi - 16384;
        int n = i2 >> 7, k = i2 & 127;
        w2T[i2] = f2bf(w2[k * 64 + n]);
    } else if (gi < 24576 + 32) {           // sentinels for spmm overread
        epkS[E + (gi - 24576)] = make_int2(0, 0);
    } else if (gi == 24576 + 32) {
        rowptr[N] = E;
    }
    // ---- histogram ----
    __shared__ int lh[MAXB];
    for (int i = tid; i < B; i += 256) lh[i] = 0;
    __syncthreads();
    const int base = blockIdx.x * 4096;
#pragma unroll
    for (int j = 0; j < 16; ++j) {
        int i = base + j * 256 + tid;
        if (i < E) atomicAdd(&lh[arow[i] >> 7], 1);
    }
    __syncthreads();
    for (int i = tid; i < B; i += 256) {
        int c = lh[i];
        if (c) atomicAdd(&counts[i], c);
    }
}

// ---- single-block exclusive scan over bucket counts -----------------------
__global__ __launch_bounds__(256) void scan_s(const int* __restrict__ counts,
                                              int* __restrict__ boff,
                                              int* __restrict__ gcursor, int B, int E) {
    __shared__ int lds[256];
    const int t = threadIdx.x;
    const int b0 = t * 4;
    int v[4];
    int s = 0;
#pragma unroll
    for (int j = 0; j < 4; ++j) {
        v[j] = (b0 + j < B) ? counts[b0 + j] : 0;
        s += v[j];
    }
    lds[t] = s;
    __syncthreads();
    for (int off = 1; off < 256; off <<= 1) {
        int tmp = 0;
        if (t >= off) tmp = lds[t - off];
        __syncthreads();
        if (t >= off) lds[t] += tmp;
        __syncthreads();
    }
    int run = (t > 0) ? lds[t - 1] : 0;
#pragma unroll
    for (int j = 0; j < 4; ++j) {
        if (b0 + j < B) {
            boff[b0 + j] = run;
            gcursor[b0 + j] = run;
        }
        run += v[j];
    }
    if (t == 255) boff[B] = E;
}

// ---- pass 1: bucket-order edges with LDS staging (coalesced out) ----------
__global__ __launch_bounds__(256) void partition_k(const int* __restrict__ arow,
                                                   const int* __restrict__ acol,
                                                   const float* __restrict__ aval,
                                                   int* __restrict__ gcursor,
                                                   int2* __restrict__ epk, int E, int B) {
    __shared__ int2 ldata[4096];
    __shared__ int ldest[4096];
    __shared__ int lhist[MAXB];
    __shared__ int lscan[MAXB];
    __shared__ int ldelta[MAXB];
    __shared__ int lcur[MAXB];
    __shared__ int stmp[256];
    const int tid = threadIdx.x;
    const int base = blockIdx.x * 4096;
    const int cnt = min(4096, E - base);

    for (int i = tid; i < MAXB; i += 256) {
        lhist[i] = 0;
        lcur[i] = 0;
    }
    __syncthreads();

    int rr[16];
#pragma unroll
    for (int j = 0; j < 16; ++j) {
        int i = base + j * 256 + tid;
        rr[j] = (i < E) ? arow[i] : -1;
        if (rr[j] >= 0) atomicAdd(&lhist[rr[j] >> 7], 1);
    }
    __syncthreads();

    const int b0 = tid * 4;
    int v[4];
    int s = 0;
#pragma unroll
    for (int j = 0; j < 4; ++j) {
        v[j] = (b0 + j < MAXB) ? lhist[b0 + j] : 0;
        s += v[j];
    }
    stmp[tid] = s;
    __syncthreads();
    for (int off = 1; off < 256; off <<= 1) {
        int tmp = 0;
        if (tid >= off) tmp = stmp[tid - off];
        __syncthreads();
        if (tid >= off) stmp[tid] += tmp;
        __syncthreads();
    }
    int run = (tid > 0) ? stmp[tid - 1] : 0;
#pragma unroll
    for (int j = 0; j < 4; ++j) {
        if (b0 + j < MAXB) lscan[b0 + j] = run;
        run += v[j];
    }
    __syncthreads();

    for (int b = tid; b < B; b += 256) {
        int c = lhist[b];
        if (c) ldelta[b] = atomicAdd(&gcursor[b], c) - lscan[b];
    }
    __syncthreads();

#pragma unroll
    for (int j = 0; j < 16; ++j) {
        int i = base + j * 256 + tid;
        if (i < E) {
            int r = rr[j];
            int b = r >> 7;
            int lp = atomicAdd(&lcur[b], 1);
            int slot = lscan[b] + lp;
            int pk = acol[i] | ((r & 127) << 17);
            ldata[slot] = make_int2(pk, __float_as_int(aval[i]));
            ldest[slot] = ldelta[b] + slot;
        }
    }
    __syncthreads();

    for (int s2 = tid; s2 < cnt; s2 += 256) epk[ldest[s2]] = ldata[s2];
}

// ---- MFMA GEMM body (global A): y_bf16[M x NC] = A[M x 128] @ W[128 x NC] -
template <int NC, bool AF32>
__device__ __forceinline__ void gemm_body(const void* __restrict__ A,
                                          const unsigned short* __restrict__ wT,
                                          unsigned short* __restrict__ y, int M,
                                          int bid, char* smem) {
    constexpr int KP = 136;
    constexpr int NT = NC / 16;
    unsigned short* wl = (unsigned short*)smem;
    const int tid = threadIdx.x;
    for (int idx = tid; idx < NC * 16; idx += 256) {
        int n = idx >> 4, kc = idx & 15;
        *(uint4*)&wl[n * KP + kc * 8] = *(const uint4*)&wT[n * 128 + kc * 8];
    }
    __syncthreads();

    const int wave = tid >> 6;
    const int lane = tid & 63;
    const int m = lane & 15;
    const int q = lane >> 4;
    const int rowbase = bid * 64 + wave * 16;
    const int rowc = min(rowbase + m, M - 1);

    v4f acc[NT] = {};
    union LU { uint4 qv; v8bf b; };

#pragma unroll
    for (int ks = 0; ks < 4; ++ks) {
        const int k0 = ks * 32 + q * 8;
        v8bf a;
        if (AF32) {
            const float* Ap = (const float*)A + (size_t)rowc * 128 + k0;
            float4 f0 = *(const float4*)Ap;
            float4 f1 = *(const float4*)(Ap + 4);
            union { unsigned short s[8]; v8bf b; } cv;
            cv.s[0] = f2bf(f0.x); cv.s[1] = f2bf(f0.y);
            cv.s[2] = f2bf(f0.z); cv.s[3] = f2bf(f0.w);
            cv.s[4] = f2bf(f1.x); cv.s[5] = f2bf(f1.y);
            cv.s[6] = f2bf(f1.z); cv.s[7] = f2bf(f1.w);
            a = cv.b;
        } else {
            LU lu;
            lu.qv = *(const uint4*)((const unsigned short*)A + (size_t)rowc * 128 + k0);
            a = lu.b;
        }
#pragma unroll
        for (int nt = 0; nt < NT; ++nt) {
            v8bf b = *(const v8bf*)&wl[(nt * 16 + m) * KP + k0];
            acc[nt] = __builtin_amdgcn_mfma_f32_16x16x32_bf16(a, b, acc[nt], 0, 0, 0);
        }
    }
#pragma unroll
    for (int nt = 0; nt < NT; ++nt) {
#pragma unroll
        for (int r = 0; r < 4; ++r) {
            int orow = rowbase + q * 4 + r;
            if (orow < M) y[(size_t)orow * NC + nt * 16 + m] = f2bf(acc[nt][r]);
        }
    }
}

// ---- fused: bucket_sort (blocks [0,B)) || gemm1 (blocks [B, B+gb)) --------
__global__ __launch_bounds__(256) void sort_gemm1(const int* __restrict__ boff,
                                                  const int2* __restrict__ epk,
                                                  int2* __restrict__ epkS,
                                                  int* __restrict__ rowptr, int N, int B,
                                                  const float* __restrict__ x,
                                                  const unsigned short* __restrict__ w1T,
                                                  unsigned short* __restrict__ y1b) {
    __shared__ __align__(16) char smem[34816];
    const int tid = threadIdx.x;
    if (blockIdx.x >= B) {
        gemm_body<128, true>(x, w1T, y1b, N, blockIdx.x - B, smem);
        return;
    }
    // ---- bucket_sort: per-bucket LDS counting sort by local row ----
    int2* sorted = (int2*)smem;                  // 4096 * 8 = 32768
    int*  sc     = (int*)(smem + 32768);         // 128 * 4
    int*  lcur   = (int*)(smem + 32768 + 512);   // 128 * 4
    const int b = blockIdx.x;
    const int s = boff[b], e = boff[b + 1];
    const int cnt = min(e - s, 4096);
    if (tid < 128) sc[tid] = 0;
    __syncthreads();
    for (int i = s + tid; i < e; i += 256) {
        int rl = (epk[i].x >> 17) & 127;
        atomicAdd(&sc[rl], 1);
    }
    __syncthreads();
    int hv = (tid < 128) ? sc[tid] : 0;
    for (int off = 1; off < 128; off <<= 1) {
        int add = 0;
        if (tid < 128 && tid >= off) add = sc[tid - off];
        __syncthreads();
        if (tid < 128 && tid >= off) sc[tid] += add;
        __syncthreads();
    }
    if (tid < 128) {
        int ex = sc[tid] - hv;  // exclusive
        lcur[tid] = ex;
        int r = b * 128 + tid;
        if (r < N) rowptr[r] = s + ex;
    }
    __syncthreads();
    for (int i = s + tid; i < e; i += 256) {
        int2 p = epk[i];
        int rl = (p.x >> 17) & 127;
        int slot = atomicAdd(&lcur[rl], 1);
        if (slot < 4096) sorted[slot] = make_int2(p.x & 0x1FFFF, p.y);
    }
    __syncthreads();
    for (int i = tid; i < cnt; i += 256) epkS[s + i] = sorted[i];
}

// ---- fused spmm1 + gemm2: block = 64 rows ---------------------------------
// Phase 1: wave w computes h1 rows [base+16w, base+16w+16): 8-deep pipelined
//   gathers of y1b (dword/lane = ch{2l,2l+1}); relu(acc+b1) -> bf16 LDS tile
//   (padded stride 136 shorts).
// Phase 2: y2 tile = h1_tile @ w2 via MFMA; A-frags from LDS, B-frags from
//   L2-resident w2T (16 KB, every block reads the same lines).
__global__ __launch_bounds__(256) void spmm_gemm2(const int* __restrict__ rowptr,
                                                  const int2* __restrict__ ep,
                                                  const unsigned short* __restrict__ y1b,
                                                  const float* __restrict__ b1,
                                                  const unsigned short* __restrict__ w2T,
                                                  unsigned short* __restrict__ y2b, int N) {
    constexpr int KP = 136;
    __shared__ unsigned short h1[64 * KP];  // 17408 B
    const int tid = threadIdx.x;
    const int wave = tid >> 6, lane = tid & 63;
    const int rowbase = blockIdx.x * 64;
    const unsigned* y32 = (const unsigned*)y1b;
    const float2 bv = ((const float2*)b1)[lane];

    for (int i = 0; i < 16; ++i) {
        const int r = rowbase + wave * 16 + i;
        float accx = 0.f, accy = 0.f;
        if (r < N) {
            const int s = rowptr[r], e = rowptr[r + 1];
            int2 cur[8];
#pragma unroll
            for (int k = 0; k < 8; ++k) cur[k] = ep[s + k];
            for (int j = s; j < e; j += 8) {
                int2 nxt[8];
#pragma unroll
                for (int k = 0; k < 8; ++k) nxt[k] = ep[j + 8 + k];
#pragma unroll
                for (int k = 0; k < 8; ++k) {
                    float v = (j + k < e) ? __int_as_float(cur[k].y) : 0.f;
                    unsigned u = y32[(size_t)cur[k].x * 64 + lane];
                    accx += v * __uint_as_float(u << 16);
                    accy += v * __uint_as_float(u & 0xffff0000u);
                }
#pragma unroll
                for (int k = 0; k < 8; ++k) cur[k] = nxt[k];
            }
        }
        accx = fmaxf(accx + bv.x, 0.f);
        accy = fmaxf(accy + bv.y, 0.f);
        unsigned pk = ((unsigned)f2bf(accy) << 16) | f2bf(accx);
        *(unsigned*)&h1[(wave * 16 + i) * KP + 2 * lane] = pk;
    }
    __syncthreads();

    // ---- phase 2: MFMA ----
    const int m = lane & 15, q = lane >> 4;
    v4f acc[4] = {};
#pragma unroll
    for (int ks = 0; ks < 4; ++ks) {
        const int k0 = ks * 32 + q * 8;
        v8bf a = *(const v8bf*)&h1[(wave * 16 + m) * KP + k0];
#pragma unroll
        for (int nt = 0; nt < 4; ++nt) {
            v8bf b = *(const v8bf*)&w2T[(nt * 16 + m) * 128 + k0];
            acc[nt] = __builtin_amdgcn_mfma_f32_16x16x32_bf16(a, b, acc[nt], 0, 0, 0);
        }
    }
#pragma unroll
    for (int nt = 0; nt < 4; ++nt) {
#pragma unroll
        for (int r = 0; r < 4; ++r) {
            int orow = rowbase + wave * 16 + q * 4 + r;
            if (orow < N) y2b[(size_t)orow * 64 + nt * 16 + m] = f2bf(acc[nt][r]);
        }
    }
}

// ---- SPMM CH=64: full wave per edge, ushort gathers, 8-deep ---------------
__global__ __launch_bounds__(256) void spmm64(const int* __restrict__ rowptr,
                                              const int2* __restrict__ ep,
                                              const unsigned short* __restrict__ yb,
                                              const float* __restrict__ bias,
                                              float* __restrict__ outp, int N) {
    const int row = (blockIdx.x * 256 + threadIdx.x) >> 6;
    const int lane = threadIdx.x & 63;
    if (row >= N) return;
    const int s = rowptr[row], e = rowptr[row + 1];
    float acc = 0.f;
    int2 cur[8];
#pragma unroll
    for (int k = 0; k < 8; ++k) cur[k] = ep[s + k];
    for (int j = s; j < e; j += 8) {
        int2 nxt[8];
#pragma unroll
        for (int k = 0; k < 8; ++k) nxt[k] = ep[j + 8 + k];
#pragma unroll
        for (int k = 0; k < 8; ++k) {
            float v = (j + k < e) ? __int_as_float(cur[k].y) : 0.f;
            unsigned u = yb[(size_t)cur[k].x * 64 + lane];
            acc += v * __uint_as_float(u << 16);
        }
#pragma unroll
        for (int k = 0; k < 8; ++k) cur[k] = nxt[k];
    }
    acc += bias[lane];
    outp[(size_t)row * 64 + lane] = acc;
}

// ---------------------------------------------------------------------------
extern "C" void kernel_launch(void* const* d_in, const int* in_sizes, int n_in,
                              void* d_out, int out_size, void* d_ws, size_t ws_size,
                              hipStream_t stream) {
    const float* x    = (const float*)d_in[0];
    const int*   arow = (const int*)d_in[1];
    const int*   acol = (const int*)d_in[2];
    const float* aval = (const float*)d_in[3];
    const float* w1   = (const float*)d_in[4];
    const float* b1   = (const float*)d_in[5];
    const float* w2   = (const float*)d_in[6];
    const float* b2   = (const float*)d_in[7];
    float*       out  = (float*)d_out;

    const int N = in_sizes[0] / 128;   // 100000
    const int E = in_sizes[1];         // 1600000
    const int B = (N + 127) >> 7;      // 782 buckets of 128 rows

    char* p = (char*)d_ws;
    auto alloc = [&](size_t bytes) {
        char* r = p;
        p += (bytes + 255) & ~(size_t)255;
        return r;
    };
    int*            counts  = (int*)alloc((size_t)MAXB * 4);
    int*            boff    = (int*)alloc((size_t)(MAXB + 1) * 4);
    int*            gcursor = (int*)alloc((size_t)MAXB * 4);
    int*            rowptr  = (int*)alloc((size_t)(N + 1) * 4);
    int2*           epkS    = (int2*)alloc((size_t)(E + 32) * 8);
    unsigned short* w1T     = (unsigned short*)alloc(128 * 128 * 2);
    unsigned short* w2T     = (unsigned short*)alloc(64 * 128 * 2);
    unsigned short* y1b     = (unsigned short*)alloc((size_t)N * 128 * 2);
    int2*           epk     = (int2*)alloc((size_t)E * 8);
    unsigned short* y2b     = (unsigned short*)alloc((size_t)N * 64 * 2);

    const int gemm_blocks = (N + 63) / 64;   // 1563
    const int pb = (E + 4095) / 4096;        // 391

    hipMemsetAsync(counts, 0, (size_t)MAXB * 4, stream);
    hist_prep<<<pb, 256, 0, stream>>>(arow, counts, E, B, w1, w2, w1T, w2T,
                                      rowptr, epkS, N);
    scan_s<<<1, 256, 0, stream>>>(counts, boff, gcursor, B, E);
    partition_k<<<pb, 256, 0, stream>>>(arow, acol, aval, gcursor, epk, E, B);
    sort_gemm1<<<B + gemm_blocks, 256, 0, stream>>>(boff, epk, epkS, rowptr, N, B,
                                                    x, w1T, y1b);
    spmm_gemm2<<<gemm_blocks, 256, 0, stream>>>(rowptr, epkS, y1b, b1, w2T, y2b, N);
    const int spmm_blocks = (N + 3) / 4;
    spmm64<<<spmm_blocks, 256, 0, stream>>>(rowptr, epkS, y2b, b2, out, N);
}